// Round 3
// baseline (874.816 us; speedup 1.0000x reference)
//
#include <hip/hip_runtime.h>
#include <hip/hip_bf16.h>
#include <stdint.h>

#define IN_F 128
#define EDGE_F 6
#define TILE_E 4096      // hist/scatter tile; K1 hist blocks and K2 blocks MUST share this mapping
#define NBIN_PAD 1024    // coarse bins = dst>>6, padded (n_nodes <= 65536 assumed; N=50000 -> 782 bins)

using bf16x8 = __attribute__((ext_vector_type(8))) short;  // 8 bf16 = 4 VGPRs
using f32x4  = __attribute__((ext_vector_type(4))) float;

__device__ __forceinline__ float bf2f(unsigned short u) {
    return __uint_as_float(((unsigned int)u) << 16);
}
__device__ __forceinline__ unsigned short f2bfbits(float f) {
    __hip_bfloat16 h = __float2bfloat16(f);  // RNE
    return *reinterpret_cast<unsigned short*>(&h);
}
__device__ __forceinline__ unsigned int packbf(float a, float b) {
    return ((unsigned int)f2bfbits(b) << 16) | (unsigned int)f2bfbits(a);
}

// ---- K1: payload pack + nf cast + LDS-privatized coarse histogram + weight pack ----
// ZERO scattered global atomics. Blocks 0..nblk_e-1 additionally count a
// 4096-edge tile into a 782-bin LDS histogram (bin = dst>>6) and write one
// 2KB ushort row of the partial matrix. Block eb does the weight pack.
__global__ __launch_bounds__(256) void pack_hist_cast(
        const int* __restrict__ eidx, const float* __restrict__ ef,
        uint4* __restrict__ efp, unsigned short* __restrict__ pmat,
        int n_edges, int nblk_e, int n_cast, int eb,
        const float* __restrict__ nf, unsigned short* __restrict__ nfb,
        const float* __restrict__ W, const float* __restrict__ b,
        const float* __restrict__ We, const float* __restrict__ be,
        unsigned short* __restrict__ Wpack, float* __restrict__ W2pack) {
    const int tid = threadIdx.x;
    const int blk = blockIdx.x;
    __shared__ int hist[NBIN_PAD];

    if (blk == eb) {
        // Wpack: idx=((kb*8+ft)*64+lane)*8+j -> bf16(W[kb*32+(lane>>4)*8+j][ft*16+(lane&15)])
        for (int idx = tid; idx < 16384; idx += 256) {
            int j = idx & 7, lane = (idx >> 3) & 63, ft = (idx >> 9) & 7, kb = idx >> 12;
            int k = kb * 32 + (lane >> 4) * 8 + j;
            int f = ft * 16 + (lane & 15);
            Wpack[idx] = f2bfbits(W[k * 128 + f]);
        }
        for (int idx = tid; idx < 1024; idx += 256) {
            int j = idx >> 7, f = idx & 127;
            float w = 0.f;
            if (j < 6)       w = We[j * 128 + f];
            else if (j == 6) w = b[f] + be[f];
            W2pack[idx] = w;
        }
    } else {
        const bool hb = (blk < nblk_e);   // block-uniform
        if (hb) {
            for (int k = tid; k < NBIN_PAD; k += 256) hist[k] = 0;
            __syncthreads();
        }
        // pack tile: 256 edges/block, e-order, coalesced. src,dst < 65536 so
        // dst rides in the high half of q.x; downstream never re-reads eidx.
        const int t = blk * 256 + tid;
        if (t < n_edges) {
            const int2 pr = reinterpret_cast<const int2*>(eidx)[t];  // (src, dst)
            const float2* efs = reinterpret_cast<const float2*>(ef + (size_t)t * EDGE_F);
            const float2 f0 = efs[0], f1 = efs[1], f2 = efs[2];
            uint4 q;
            q.x = (unsigned int)pr.x | ((unsigned int)pr.y << 16);
            q.y = packbf(f0.x, f0.y);
            q.z = packbf(f1.x, f1.y);
            q.w = packbf(f2.x, f2.y);
            efp[t] = q;
        }
        // coarse histogram tile (LDS atomics only)
        if (hb) {
            const int e0 = blk * TILE_E;
#pragma unroll
            for (int i = 0; i < TILE_E / 256; ++i) {
                const int e = e0 + i * 256 + tid;
                if (e < n_edges) {
                    const int dst = reinterpret_cast<const int2*>(eidx)[e].y;
                    atomicAdd(&hist[dst >> 6], 1);
                }
            }
            __syncthreads();
            for (int k = tid; k < NBIN_PAD; k += 256)
                pmat[(size_t)blk * NBIN_PAD + k] = (unsigned short)hist[k];
        }
    }
    // nf -> bf16 cast rides along (grid-stride; ~1 unit/thread at E=800K)
    const int t = blk * 256 + tid;
    const int stride = gridDim.x * 256;
    for (int i = t; i < n_cast; i += stride) {
        const float4 lo = reinterpret_cast<const float4*>(nf)[2 * i];
        const float4 hi = reinterpret_cast<const float4*>(nf)[2 * i + 1];
        uint4 o;
        o.x = packbf(lo.x, lo.y); o.y = packbf(lo.z, lo.w);
        o.z = packbf(hi.x, hi.y); o.w = packbf(hi.z, hi.w);
        reinterpret_cast<uint4*>(nfb)[i] = o;
    }
}

// ---- K2: coarse scatter into 64-dst buckets. No global atomics. ----
// Each block reconstructs its per-bin start cursor from the partial matrix
// (400 KB, L2-broadcast): cursor[b] = base[b] + sum_{b'<blk} pmat[b'][b].
// Same tile mapping as K1's hist blocks -> counts match scatters exactly ->
// slots form a bijection. Each thread owns 4 bins for the 782-wide scan.
__global__ __launch_bounds__(256) void coarse_scatter(
        const uint4* __restrict__ efp, const unsigned short* __restrict__ pmat,
        uint4* __restrict__ rec_c, int* __restrict__ gbase,
        int n_edges, int nblk_e) {
    const int tid = threadIdx.x;
    const int blk = blockIdx.x;
    __shared__ int cur[NBIN_PAD];
    __shared__ int sc[256];
    int tot[4] = {0, 0, 0, 0}, pre[4] = {0, 0, 0, 0};
#pragma unroll 4
    for (int bb = 0; bb < nblk_e; ++bb) {
        const ushort4 v =
            reinterpret_cast<const ushort4*>(pmat + (size_t)bb * NBIN_PAD)[tid];
        tot[0] += v.x; tot[1] += v.y; tot[2] += v.z; tot[3] += v.w;
        if (bb < blk) { pre[0] += v.x; pre[1] += v.y; pre[2] += v.z; pre[3] += v.w; }
    }
    const int tsum = tot[0] + tot[1] + tot[2] + tot[3];
    sc[tid] = tsum;
    __syncthreads();
    for (int off = 1; off < 256; off <<= 1) {  // inclusive scan of thread sums
        int t2 = (tid >= off) ? sc[tid - off] : 0;
        __syncthreads();
        sc[tid] += t2;
        __syncthreads();
    }
    const int texcl = sc[tid] - tsum;
    int bexcl[4];
    bexcl[0] = texcl;
    bexcl[1] = texcl + tot[0];
    bexcl[2] = bexcl[1] + tot[1];
    bexcl[3] = bexcl[2] + tot[2];
#pragma unroll
    for (int j = 0; j < 4; ++j) {
        cur[4 * tid + j] = bexcl[j] + pre[j];
        if (blk == 0) gbase[4 * tid + j] = bexcl[j];   // padded bins -> n_edges
    }
    if (blk == 0 && tid == 255) gbase[NBIN_PAD] = bexcl[3] + tot[3];  // = n_edges
    __syncthreads();
    const int e0 = blk * TILE_E;
#pragma unroll
    for (int i = 0; i < TILE_E / 256; ++i) {
        const int e = e0 + i * 256 + tid;
        if (e < n_edges) {
            const uint4 q = efp[e];
            const int cb = q.x >> 22;          // dst>>6 (dst = q.x>>16, 16-bit)
            const int pos = atomicAdd(&cur[cb], 1);
            rec_c[pos] = q;
        }
    }
}

// ---- K3: streaming bucket aggregate. Replaces fine_rank + aggregate_bf16. ----
// One 512-thread block per 64-dst bucket (grid 782, ~3 blk/CU, ~24 waves/CU).
// Fix for round-2's regression: NO per-dst pipeline drains -- each wave
// streams 8-record batches continuously (16 batches/wave at sz~1023) and
// accumulates into LDS fp32 via ds_add_f32. Even/odd feature split
// (acc[d][f'] with f'=(f&1)*64+(f>>1)) makes every LDS atomic 2-way on banks
// (free, m136) AND maps 1:1 onto both the packed gather word (lane's uint =
// feats 2l,2l+1) and the packed S write. Records are read exactly once; no
// index lists, no overflow path, no sorted rec, no rowptr.
__global__ __launch_bounds__(512) void bucket_agg(
        const uint4* __restrict__ rec_c, const int* __restrict__ gbase,
        const unsigned short* __restrict__ nfb,
        unsigned short* __restrict__ S, unsigned short* __restrict__ E8,
        int n_nodes) {
    __shared__ float accN[64 * 128];   // 32 KB, even/odd-split feature layout
    __shared__ float accE[64 * 8];     // 2 KB: e0..e5, deg, pad
    const int tid = threadIdx.x;
    for (int k = tid; k < 64 * 128; k += 512) accN[k] = 0.f;
    for (int k = tid; k < 64 * 8; k += 512) accE[k] = 0.f;
    __syncthreads();
    const int c = blockIdx.x;
    const int rbase = gbase[c], rend = gbase[c + 1];
    const int sz = rend - rbase;
    const int lane = tid & 63;
    const int wv = __builtin_amdgcn_readfirstlane(tid >> 6);
    const int nb = sz >> 3;            // full 8-batches
    for (int bidx = wv; bidx < nb; bidx += 8) {
        const int i0 = __builtin_amdgcn_readfirstlane(rbase + bidx * 8);
        uint4 q[8];
        unsigned int u[8];
#pragma unroll
        for (int j = 0; j < 8; ++j) q[j] = rec_c[i0 + j];        // SGPR, wave-uniform
#pragma unroll
        for (int j = 0; j < 8; ++j)
            u[j] = reinterpret_cast<const unsigned int*>(
                nfb + (size_t)(q[j].x & 0xFFFFu) * IN_F)[lane];
#pragma unroll
        for (int j = 0; j < 8; ++j) {
            const int d = (q[j].x >> 16) & 63;
            atomicAdd(&accN[d * 128 + lane], bf2f((unsigned short)u[j]));
            atomicAdd(&accN[d * 128 + 64 + lane], bf2f((unsigned short)(u[j] >> 16)));
            const unsigned int w = (lane < 2) ? q[j].y : (lane < 4) ? q[j].z : q[j].w;
            const unsigned short h =
                (lane & 1) ? (unsigned short)(w >> 16) : (unsigned short)w;
            if (lane < 7)
                atomicAdd(&accE[d * 8 + lane], (lane == 6) ? 1.0f : bf2f(h));
        }
    }
    if (wv == (nb & 7)) {  // <=7 leftover records, one wave
        for (int i = rbase + nb * 8; i < rend; ++i) {
            const int ii = __builtin_amdgcn_readfirstlane(i);
            const uint4 q0 = rec_c[ii];
            const unsigned int u0 = reinterpret_cast<const unsigned int*>(
                nfb + (size_t)(q0.x & 0xFFFFu) * IN_F)[lane];
            const int d = (q0.x >> 16) & 63;
            atomicAdd(&accN[d * 128 + lane], bf2f((unsigned short)u0));
            atomicAdd(&accN[d * 128 + 64 + lane], bf2f((unsigned short)(u0 >> 16)));
            const unsigned int w = (lane < 2) ? q0.y : (lane < 4) ? q0.z : q0.w;
            const unsigned short h =
                (lane & 1) ? (unsigned short)(w >> 16) : (unsigned short)w;
            if (lane < 7)
                atomicAdd(&accE[d * 8 + lane], (lane == 6) ? 1.0f : bf2f(h));
        }
    }
    __syncthreads();
    // write-out: wave wv owns dsts wv*8..wv*8+7; LDS reads 2-way (free)
#pragma unroll
    for (int k = 0; k < 8; ++k) {
        const int d = wv * 8 + k;
        const int n = c * 64 + d;
        if (n >= n_nodes) continue;
        const unsigned int val =
            packbf(accN[d * 128 + lane], accN[d * 128 + 64 + lane]);
        reinterpret_cast<unsigned int*>(S + (size_t)n * IN_F)[lane] = val;
        if (lane == 0) {
            uint4 qq;
            qq.x = packbf(accE[d * 8 + 0], accE[d * 8 + 1]);
            qq.y = packbf(accE[d * 8 + 2], accE[d * 8 + 3]);
            qq.z = packbf(accE[d * 8 + 4], accE[d * 8 + 5]);
            qq.w = packbf(accE[d * 8 + 6], 0.f);   // deg exact in bf16 (small)
            *reinterpret_cast<uint4*>(E8 + (size_t)n * 8) = qq;
        }
    }
}

// ---- K4: MFMA GEMM  out = relu( S[N,128]bf16 @ W[128,128]bf16 + E-term ) ----
__global__ __launch_bounds__(256) void gemm_mfma(
        const unsigned short* __restrict__ S, const unsigned short* __restrict__ E8,
        const unsigned short* __restrict__ Wpack, const float* __restrict__ W2pack,
        float* __restrict__ out, int n_nodes) {
    __shared__ __align__(16) short Wl[16384];   // 32 KB, B-fragment layout
    __shared__ float W2l[1024];                 // 4 KB
    const int tid = threadIdx.x;
    for (int i = tid; i < 2048; i += 256)
        reinterpret_cast<uint4*>(Wl)[i] = reinterpret_cast<const uint4*>(Wpack)[i];
    for (int i = tid; i < 1024; i += 256) W2l[i] = W2pack[i];

    const int wv = tid >> 6, lane = tid & 63;
    const int m = lane & 15, quad = lane >> 4;
    const int n0 = blockIdx.x * 64 + wv * 16;

    const int arow = min(n0 + m, n_nodes - 1);
    const unsigned short* ap = S + (size_t)arow * IN_F + quad * 8;
    bf16x8 a[4];
#pragma unroll
    for (int kb = 0; kb < 4; ++kb)
        a[kb] = *reinterpret_cast<const bf16x8*>(ap + kb * 32);

    __syncthreads();

    f32x4 acc[8];
#pragma unroll
    for (int ft = 0; ft < 8; ++ft) acc[ft] = (f32x4){0.f, 0.f, 0.f, 0.f};

#pragma unroll
    for (int kb = 0; kb < 4; ++kb) {
#pragma unroll
        for (int ft = 0; ft < 8; ++ft) {
            const bf16x8 bfrag =
                reinterpret_cast<const bf16x8*>(Wl)[(kb * 8 + ft) * 64 + lane];
            acc[ft] = __builtin_amdgcn_mfma_f32_16x16x32_bf16(a[kb], bfrag, acc[ft], 0, 0, 0);
        }
    }

    // Epilogue. C/D layout: col=lane&15, row=quad*4+reg.
    float e[4][7];
#pragma unroll
    for (int r = 0; r < 4; ++r) {
        const int n = min(n0 + quad * 4 + r, n_nodes - 1);
        const uint4 q = *reinterpret_cast<const uint4*>(E8 + (size_t)n * 8);
        e[r][0] = bf2f((unsigned short)q.x); e[r][1] = bf2f((unsigned short)(q.x >> 16));
        e[r][2] = bf2f((unsigned short)q.y); e[r][3] = bf2f((unsigned short)(q.y >> 16));
        e[r][4] = bf2f((unsigned short)q.z); e[r][5] = bf2f((unsigned short)(q.z >> 16));
        e[r][6] = bf2f((unsigned short)q.w);  // deg
    }
#pragma unroll
    for (int ft = 0; ft < 8; ++ft) {
        const int f = ft * 16 + m;
        float w2[7];
#pragma unroll
        for (int j = 0; j < 7; ++j) w2[j] = W2l[j * 128 + f];
#pragma unroll
        for (int r = 0; r < 4; ++r) {
            const int n = n0 + quad * 4 + r;
            if (n < n_nodes) {
                float v = acc[ft][r];
#pragma unroll
                for (int j = 0; j < 7; ++j) v += e[r][j] * w2[j];
                out[(size_t)n * 128 + f] = fmaxf(v, 0.f);
            }
        }
    }
}

extern "C" void kernel_launch(void* const* d_in, const int* in_sizes, int n_in,
                              void* d_out, int out_size, void* d_ws, size_t ws_size,
                              hipStream_t stream) {
    const float* nf = (const float*)d_in[0];  // fp32 (N,128)
    const int* eidx = (const int*)d_in[1];    // int32 (E,2)
    const float* ef = (const float*)d_in[2];  // fp32 (E,6)
    const float* W  = (const float*)d_in[3];  // fp32 (128,128)
    const float* b  = (const float*)d_in[4];  // fp32 (128,)
    const float* We = (const float*)d_in[5];  // fp32 (6,128)
    const float* be = (const float*)d_in[6];  // fp32 (128,)
    float* out = (float*)d_out;               // fp32 (N,128)

    const int n_nodes = in_sizes[0] / IN_F;
    const int n_edges = in_sizes[1] / 2;

    const int eb = (n_edges + 255) / 256;                 // 3125 pack blocks
    const int nblk_e = (n_edges + TILE_E - 1) / TILE_E;   // 196 hist/scatter blocks
    const int nbin2 = (n_nodes + 63) / 64;                // 782 fine buckets
    const int n_cast = n_nodes * (IN_F / 8);

    // ws (~53 MB): efp | rec_c (16B*E each) | S | E8 | Wpack | W2pack
    //   | pmat (nblk_e*1024 ushort) | gbase (1028 int) | nfb
    uint4* efp   = (uint4*)d_ws;
    uint4* rec_c = efp + n_edges;
    unsigned short* S = (unsigned short*)(rec_c + n_edges);
    unsigned short* E8 = S + (size_t)n_nodes * IN_F;
    unsigned short* Wpack = E8 + (size_t)n_nodes * 8;
    float* W2pack = (float*)(Wpack + 16384);
    unsigned short* pmat = (unsigned short*)(W2pack + 1024);
    int* gbase = (int*)(pmat + (size_t)nblk_e * NBIN_PAD);
    unsigned short* nfb = (unsigned short*)(gbase + 1028);

    // No memset needed: pmat rows fully written, all cursors derived in-LDS.
    pack_hist_cast<<<eb + 1, 256, 0, stream>>>(eidx, ef, efp, pmat,
                                               n_edges, nblk_e, n_cast, eb,
                                               nf, nfb, W, b, We, be, Wpack, W2pack);
    coarse_scatter<<<nblk_e, 256, 0, stream>>>(efp, pmat, rec_c, gbase,
                                               n_edges, nblk_e);
    bucket_agg<<<nbin2, 512, 0, stream>>>(rec_c, gbase, nfb, S, E8, n_nodes);
    gemm_mfma<<<(n_nodes + 63) / 64, 256, 0, stream>>>(S, E8, Wpack, W2pack, out, n_nodes);
}

// Round 4
// 194.807 us; speedup vs baseline: 4.4907x; 4.4907x over previous
//
#include <hip/hip_runtime.h>
#include <hip/hip_bf16.h>
#include <stdint.h>

#define IN_F 128
#define EDGE_F 6
#define TILE_E 4096      // hist/scatter tile; K1 hist blocks and K2 blocks MUST share this mapping
#define NBIN_PAD 256     // coarse bins = dst>>8 (n_nodes <= 65536 assumed; N=50000 -> 196 bins)
#define PADMAX 1792      // 256 dsts * 7 max pad records per dst (pad deg to multiple of 8)

using bf16x8 = __attribute__((ext_vector_type(8))) short;  // 8 bf16 = 4 VGPRs
using f32x4  = __attribute__((ext_vector_type(4))) float;

__device__ __forceinline__ float bf2f(unsigned short u) {
    return __uint_as_float(((unsigned int)u) << 16);
}
__device__ __forceinline__ unsigned short f2bfbits(float f) {
    __hip_bfloat16 h = __float2bfloat16(f);  // RNE
    return *reinterpret_cast<unsigned short*>(&h);
}
__device__ __forceinline__ unsigned int packbf(float a, float b) {
    return ((unsigned int)f2bfbits(b) << 16) | (unsigned int)f2bfbits(a);
}

// ---- K1: payload pack + nf cast + LDS-privatized coarse histogram + weight pack ----
// ZERO scattered global atomics (the old 800K atomicAdd stream was 44us of pure
// TCC-RMW dead time). Blocks 0..nblk_e-1 additionally count a 4096-edge tile
// into a 196-bin LDS histogram (cb = dst>>8) and write one 512B ushort row of
// the partial matrix. Block eb does the weight pack + zeroes the dummy nf row.
__global__ __launch_bounds__(256) void pack_hist_cast(
        const int* __restrict__ eidx, const float* __restrict__ ef,
        uint4* __restrict__ efp, unsigned short* __restrict__ pmat,
        int n_edges, int nblk_e, int n_cast, int eb, int n_nodes,
        const float* __restrict__ nf, unsigned short* __restrict__ nfb,
        const float* __restrict__ W, const float* __restrict__ b,
        const float* __restrict__ We, const float* __restrict__ be,
        unsigned short* __restrict__ Wpack, float* __restrict__ W2pack) {
    const int tid = threadIdx.x;
    const int blk = blockIdx.x;
    __shared__ int hist[NBIN_PAD];

    if (blk == eb) {
        // Wpack: idx=((kb*8+ft)*64+lane)*8+j -> bf16(W[kb*32+(lane>>4)*8+j][ft*16+(lane&15)])
        for (int idx = tid; idx < 16384; idx += 256) {
            int j = idx & 7, lane = (idx >> 3) & 63, ft = (idx >> 9) & 7, kb = idx >> 12;
            int k = kb * 32 + (lane >> 4) * 8 + j;
            int f = ft * 16 + (lane & 15);
            Wpack[idx] = f2bfbits(W[k * 128 + f]);
        }
        for (int idx = tid; idx < 1024; idx += 256) {
            int j = idx >> 7, f = idx & 127;
            float w = 0.f;
            if (j < 6)       w = We[j * 128 + f];
            else if (j == 6) w = b[f] + be[f];
            W2pack[idx] = w;
        }
        // dummy node row (index n_nodes): zero. Pad records gather from here --
        // one 256B line, instantly cache-hot, adds 0.0 to every sum.
        if (tid < 16) {
            uint4 z; z.x = z.y = z.z = z.w = 0u;
            reinterpret_cast<uint4*>(nfb + (size_t)n_nodes * IN_F)[tid] = z;
        }
    } else {
        const bool hb = (blk < nblk_e);
        if (hb) {
            hist[tid] = 0;
            __syncthreads();
        }
        // pack tile: 256 edges/block, e-order, coalesced. src,dst < 65536 so
        // dst rides in the high half of q.x; downstream never re-reads eidx.
        const int t = blk * 256 + tid;
        if (t < n_edges) {
            const int2 pr = reinterpret_cast<const int2*>(eidx)[t];  // (src, dst)
            const float2* efs = reinterpret_cast<const float2*>(ef + (size_t)t * EDGE_F);
            const float2 f0 = efs[0], f1 = efs[1], f2 = efs[2];
            uint4 q;
            q.x = (unsigned int)pr.x | ((unsigned int)pr.y << 16);
            q.y = packbf(f0.x, f0.y);
            q.z = packbf(f1.x, f1.y);
            q.w = packbf(f2.x, f2.y);
            efp[t] = q;
        }
        // coarse histogram tile (LDS atomics only)
        if (hb) {
            const int e0 = blk * TILE_E;
#pragma unroll
            for (int i = 0; i < TILE_E / 256; ++i) {
                const int e = e0 + i * 256 + tid;
                if (e < n_edges) {
                    const int dst = reinterpret_cast<const int2*>(eidx)[e].y;
                    atomicAdd(&hist[dst >> 8], 1);
                }
            }
            __syncthreads();
            pmat[(size_t)blk * NBIN_PAD + tid] = (unsigned short)hist[tid];
        }
    }
    // nf -> bf16 cast rides along (grid-stride; ~1 unit/thread at E=800K)
    const int t = blk * 256 + tid;
    const int stride = gridDim.x * 256;
    for (int i = t; i < n_cast; i += stride) {
        const float4 lo = reinterpret_cast<const float4*>(nf)[2 * i];
        const float4 hi = reinterpret_cast<const float4*>(nf)[2 * i + 1];
        uint4 o;
        o.x = packbf(lo.x, lo.y); o.y = packbf(lo.z, lo.w);
        o.z = packbf(hi.x, hi.y); o.w = packbf(hi.z, hi.w);
        reinterpret_cast<uint4*>(nfb)[i] = o;
    }
}

// ---- K2: coarse scatter into dst>>8 buckets. No global atomics. ----
// Each block reconstructs its per-bin start cursor from the partial matrix
// (100 KB, L2-broadcast): cursor[c] = base[c] + sum_{b'<blk} pmat[b'][c].
// Same tile mapping as K1's hist blocks -> counts match scatters exactly ->
// slots form a bijection. Writes have ~21-edge (336B) run locality.
__global__ __launch_bounds__(256) void coarse_scatter(
        const uint4* __restrict__ efp, const unsigned short* __restrict__ pmat,
        uint4* __restrict__ rec_c, int* __restrict__ gbase,
        int n_edges, int nblk_e, int nbin) {
    const int tid = threadIdx.x;
    const int blk = blockIdx.x;
    __shared__ int cur[NBIN_PAD];
    __shared__ int sc[NBIN_PAD];
    int tot = 0, pre = 0;
#pragma unroll 4
    for (int bb = 0; bb < nblk_e; ++bb) {
        const int v = pmat[(size_t)bb * NBIN_PAD + tid];
        tot += v;
        pre += (bb < blk) ? v : 0;
    }
    sc[tid] = tot;
    __syncthreads();
    for (int off = 1; off < 256; off <<= 1) {  // inclusive scan of totals
        int t2 = (tid >= off) ? sc[tid - off] : 0;
        __syncthreads();
        sc[tid] += t2;
        __syncthreads();
    }
    const int excl = sc[tid] - tot;            // base[tid]
    cur[tid] = excl + pre;
    if (blk == 0 && tid <= nbin) gbase[tid] = excl;  // gbase[nbin] == n_edges
    __syncthreads();
    const int e0 = blk * TILE_E;
#pragma unroll
    for (int i = 0; i < TILE_E / 256; ++i) {
        const int e = e0 + i * 256 + tid;
        if (e < n_edges) {
            const uint4 q = efp[e];
            const int cb = q.x >> 24;          // dst>>8 (dst = q.x>>16, 16-bit)
            const int pos = atomicAdd(&cur[cb], 1);
            rec_c[pos] = q;
        }
    }
}

// ---- K3: bucket-local fine counting sort -> PADDED CSR rec + pr2 ----
// One block per 256-node bucket (~4082 edges, L2-hot; 2 passes). All ranking
// via LDS. NEW vs R1: each dst's run in rec is padded to a multiple of 8 with
// dummy records (src = n_nodes -> zero row), so the aggregate kernel runs
// ONLY full 8-deep batches -- no 4-tail, no serial drain tail (the drains
// were the aggregate's concurrency leak; gather BW scales with in-flight
// count per R1-vs-R2 evidence). Padded bucket base = gbase[c] + c*PADMAX,
// provably disjoint since per-bucket pad <= 256*7. pr2[n] = {padded_start,
// true_deg} replaces rowptr.
__global__ __launch_bounds__(256) void fine_rank(
        const uint4* __restrict__ rec_c, const int* __restrict__ gbase,
        uint4* __restrict__ rec, int2* __restrict__ pr2, int n_nodes) {
    const int tid = threadIdx.x;
    const int c = blockIdx.x;
    const int rbase = gbase[c], rend = gbase[c + 1];
    const int pbase = rbase + c * PADMAX;
    __shared__ int fcnt[256];
    __shared__ int fpos[256];
    fcnt[tid] = 0;
    __syncthreads();
    for (int i = rbase + tid; i < rend; i += 256) {
        const unsigned int qx = reinterpret_cast<const unsigned int*>(rec_c)[(size_t)i * 4];
        atomicAdd(&fcnt[(qx >> 16) & 255], 1);
    }
    __syncthreads();
    const int own = fcnt[tid];
    const int ownp = (own + 7) & ~7;           // padded run length
    // inclusive scan of padded lengths (in place)
    fcnt[tid] = ownp;
    __syncthreads();
    for (int off = 1; off < 256; off <<= 1) {
        int t2 = (tid >= off) ? fcnt[tid - off] : 0;
        __syncthreads();
        fcnt[tid] += t2;
        __syncthreads();
    }
    const int pexcl = fcnt[tid] - ownp;        // padded exclusive prefix
    fpos[tid] = pexcl;
    const int n = c * 256 + tid;
    if (n < n_nodes) {
        int2 pr; pr.x = pbase + pexcl; pr.y = own;
        pr2[n] = pr;
    }
    __syncthreads();
    for (int i = rbase + tid; i < rend; i += 256) {
        const uint4 q = rec_c[i];                          // L2-hot re-read
        const int r = atomicAdd(&fpos[(q.x >> 16) & 255], 1);
        rec[pbase + r] = q;
    }
    // pad fill: thread tid owns dst tid's <=7 dummy slots (16B writes, 64KB window)
    uint4 dmy; dmy.x = (unsigned int)n_nodes; dmy.y = dmy.z = dmy.w = 0u;
    for (int j = own; j < ownp; ++j)
        rec[pbase + pexcl + j] = dmy;
}

// ---- K4: aggregate, bf16 gather (256B rows). One 64-lane wave per dst. ----
// rec[i] loads are wave-uniform -> SGPRs (cheap). Every dst run is a multiple
// of 8 records, so the wave is ALWAYS 8 gathers deep -- zero drain tails.
// Max-occupancy kernel (16 VGPR); do NOT fuse with the MFMA gemm (R12: fusion
// collapses wave count 50000->3128 and doubles total time).
__global__ __launch_bounds__(256) void aggregate_bf16(
        const unsigned short* __restrict__ nfb, const uint4* __restrict__ rec,
        const int2* __restrict__ pr2, unsigned short* __restrict__ S,
        unsigned short* __restrict__ E8, int n_nodes) {
    const int lane = threadIdx.x & 63;
    const int wv = __builtin_amdgcn_readfirstlane(threadIdx.x >> 6);
    const int n = blockIdx.x * 4 + wv;
    if (n >= n_nodes) return;
    const int2 pr = pr2[n];
    const int deg = pr.y;
    const int nb = (deg + 7) >> 3;             // all-8-deep batches (padded)
    float ax = 0.f, ay = 0.f;
    float e0 = 0.f, e1 = 0.f, e2 = 0.f, e3 = 0.f, e4 = 0.f, e5 = 0.f;
    int i = pr.x;
    for (int bb = 0; bb < nb; ++bb, i += 8) {
        uint4 q[8];
        unsigned int u[8];
#pragma unroll
        for (int j = 0; j < 8; ++j) q[j] = rec[i + j];           // SGPR, wave-uniform
#pragma unroll
        for (int j = 0; j < 8; ++j)
            u[j] = reinterpret_cast<const unsigned int*>(
                nfb + (size_t)(q[j].x & 0xFFFFu) * IN_F)[lane];
#pragma unroll
        for (int j = 0; j < 8; ++j) {
            ax += bf2f((unsigned short)u[j]);
            ay += bf2f((unsigned short)(u[j] >> 16));
            e0 += bf2f((unsigned short)q[j].y);
            e1 += bf2f((unsigned short)(q[j].y >> 16));
            e2 += bf2f((unsigned short)q[j].z);
            e3 += bf2f((unsigned short)(q[j].z >> 16));
            e4 += bf2f((unsigned short)q[j].w);
            e5 += bf2f((unsigned short)(q[j].w >> 16));
        }
    }
    unsigned short* row = S + (size_t)n * IN_F;
    reinterpret_cast<unsigned int*>(row)[lane] = packbf(ax, ay);
    if (lane == 0) {
        uint4 q;
        q.x = packbf(e0, e1);
        q.y = packbf(e2, e3);
        q.z = packbf(e4, e5);
        q.w = packbf((float)deg, 0.f);          // deg exact in bf16 (small)
        *reinterpret_cast<uint4*>(E8 + (size_t)n * 8) = q;
    }
}

// ---- K5: MFMA GEMM  out = relu( S[N,128]bf16 @ W[128,128]bf16 + E-term ) ----
__global__ __launch_bounds__(256) void gemm_mfma(
        const unsigned short* __restrict__ S, const unsigned short* __restrict__ E8,
        const unsigned short* __restrict__ Wpack, const float* __restrict__ W2pack,
        float* __restrict__ out, int n_nodes) {
    __shared__ __align__(16) short Wl[16384];   // 32 KB, B-fragment layout
    __shared__ float W2l[1024];                 // 4 KB
    const int tid = threadIdx.x;
    for (int i = tid; i < 2048; i += 256)
        reinterpret_cast<uint4*>(Wl)[i] = reinterpret_cast<const uint4*>(Wpack)[i];
    for (int i = tid; i < 1024; i += 256) W2l[i] = W2pack[i];

    const int wv = tid >> 6, lane = tid & 63;
    const int m = lane & 15, quad = lane >> 4;
    const int n0 = blockIdx.x * 64 + wv * 16;

    const int arow = min(n0 + m, n_nodes - 1);
    const unsigned short* ap = S + (size_t)arow * IN_F + quad * 8;
    bf16x8 a[4];
#pragma unroll
    for (int kb = 0; kb < 4; ++kb)
        a[kb] = *reinterpret_cast<const bf16x8*>(ap + kb * 32);

    __syncthreads();

    f32x4 acc[8];
#pragma unroll
    for (int ft = 0; ft < 8; ++ft) acc[ft] = (f32x4){0.f, 0.f, 0.f, 0.f};

#pragma unroll
    for (int kb = 0; kb < 4; ++kb) {
#pragma unroll
        for (int ft = 0; ft < 8; ++ft) {
            const bf16x8 bfrag =
                reinterpret_cast<const bf16x8*>(Wl)[(kb * 8 + ft) * 64 + lane];
            acc[ft] = __builtin_amdgcn_mfma_f32_16x16x32_bf16(a[kb], bfrag, acc[ft], 0, 0, 0);
        }
    }

    // Epilogue. C/D layout: col=lane&15, row=quad*4+reg.
    float e[4][7];
#pragma unroll
    for (int r = 0; r < 4; ++r) {
        const int n = min(n0 + quad * 4 + r, n_nodes - 1);
        const uint4 q = *reinterpret_cast<const uint4*>(E8 + (size_t)n * 8);
        e[r][0] = bf2f((unsigned short)q.x); e[r][1] = bf2f((unsigned short)(q.x >> 16));
        e[r][2] = bf2f((unsigned short)q.y); e[r][3] = bf2f((unsigned short)(q.y >> 16));
        e[r][4] = bf2f((unsigned short)q.z); e[r][5] = bf2f((unsigned short)(q.z >> 16));
        e[r][6] = bf2f((unsigned short)q.w);  // deg
    }
#pragma unroll
    for (int ft = 0; ft < 8; ++ft) {
        const int f = ft * 16 + m;
        float w2[7];
#pragma unroll
        for (int j = 0; j < 7; ++j) w2[j] = W2l[j * 128 + f];
#pragma unroll
        for (int r = 0; r < 4; ++r) {
            const int n = n0 + quad * 4 + r;
            if (n < n_nodes) {
                float v = acc[ft][r];
#pragma unroll
                for (int j = 0; j < 7; ++j) v += e[r][j] * w2[j];
                out[(size_t)n * 128 + f] = fmaxf(v, 0.f);
            }
        }
    }
}

extern "C" void kernel_launch(void* const* d_in, const int* in_sizes, int n_in,
                              void* d_out, int out_size, void* d_ws, size_t ws_size,
                              hipStream_t stream) {
    const float* nf = (const float*)d_in[0];  // fp32 (N,128)
    const int* eidx = (const int*)d_in[1];    // int32 (E,2)
    const float* ef = (const float*)d_in[2];  // fp32 (E,6)
    const float* W  = (const float*)d_in[3];  // fp32 (128,128)
    const float* b  = (const float*)d_in[4];  // fp32 (128,)
    const float* We = (const float*)d_in[5];  // fp32 (6,128)
    const float* be = (const float*)d_in[6];  // fp32 (128,)
    float* out = (float*)d_out;               // fp32 (N,128)

    const int n_nodes = in_sizes[0] / IN_F;
    const int n_edges = in_sizes[1] / 2;

    const int eb = (n_edges + 255) / 256;                 // 3125 pack blocks
    const int nblk_e = (n_edges + TILE_E - 1) / TILE_E;   // 196 hist/scatter blocks
    const int nbin = (n_nodes + 255) >> 8;                // 196 coarse buckets
    const int n_cast = n_nodes * (IN_F / 8);

    // ws (~60 MB): rec (E + nbin*PADMAX recs, padded CSR) | efp | rec_c
    //   | S | E8 | Wpack | W2pack | pmat | gbase | pr2 | nfb ((N+1) rows)
    uint4* rec   = (uint4*)d_ws;
    uint4* efp   = rec + ((size_t)n_edges + (size_t)nbin * PADMAX);
    uint4* rec_c = efp + n_edges;
    unsigned short* S = (unsigned short*)(rec_c + n_edges);
    unsigned short* E8 = S + (size_t)n_nodes * IN_F;
    unsigned short* Wpack = E8 + (size_t)n_nodes * 8;
    float* W2pack = (float*)(Wpack + 16384);
    unsigned short* pmat = (unsigned short*)(W2pack + 1024);
    int* gbase = (int*)(pmat + (size_t)nblk_e * NBIN_PAD);
    int2* pr2 = (int2*)(gbase + 260);
    unsigned short* nfb = (unsigned short*)(pr2 + n_nodes);

    // No memset needed: pmat rows fully written, all cursors derived in-LDS,
    // pad records explicitly written by fine_rank.
    pack_hist_cast<<<eb + 1, 256, 0, stream>>>(eidx, ef, efp, pmat,
                                               n_edges, nblk_e, n_cast, eb, n_nodes,
                                               nf, nfb, W, b, We, be, Wpack, W2pack);
    coarse_scatter<<<nblk_e, 256, 0, stream>>>(efp, pmat, rec_c, gbase,
                                               n_edges, nblk_e, nbin);
    fine_rank<<<nbin, 256, 0, stream>>>(rec_c, gbase, rec, pr2, n_nodes);
    aggregate_bf16<<<(n_nodes + 3) / 4, 256, 0, stream>>>(nfb, rec, pr2, S, E8, n_nodes);
    gemm_mfma<<<(n_nodes + 63) / 64, 256, 0, stream>>>(S, E8, Wpack, W2pack, out, n_nodes);
}